// Round 10
// baseline (507.129 us; speedup 1.0000x reference)
//
#include <hip/hip_runtime.h>
#include <hip/hip_bf16.h>

#define BQ 4
#define HH 56
#define WW 56
#define NN (HH*WW)      // 3136
#define CC 256
#define NHEAD 8
#define HD 32
#define PP 1376
#define PPAD 1408       // 22 * 64
#define HIDN 1024
#define EPS_LN 1e-5f
// ATT_SCALE * log2(e): scores from QK^T come out ready for exp2
#define QSCALE_LOG2E 0.25503484f

typedef unsigned short bf16u;
typedef __attribute__((ext_vector_type(8))) short short8;
typedef __attribute__((ext_vector_type(4))) float f32x4;

__device__ __forceinline__ float bf2f(bf16u u){
  union { unsigned int i; float f; } v; v.i = ((unsigned int)u) << 16; return v.f;
}
__device__ __forceinline__ bf16u f2bf(float f){
  unsigned int x = __float_as_uint(f);
  x += 0x7fffu + ((x >> 16) & 1u);
  return (bf16u)(x >> 16);
}
// cheap half-up round (2 ops) for hot paths
__device__ __forceinline__ bf16u f2bf_r(float f){
  return (bf16u)((__float_as_uint(f) + 0x8000u) >> 16);
}

// ---------------- weights -> bf16, once per launch ----------------
__global__ void k_wconv(const float* __restrict__ qw, const float* __restrict__ kvw,
                        const float* __restrict__ pw, const float* __restrict__ f1,
                        const float* __restrict__ f2, bf16u* __restrict__ o){
  int off = (blockIdx.x*256 + threadIdx.x) * 4;
  const float* s;
  if (off < 65536)       s = qw  + off;
  else if (off < 196608) s = kvw + off - 65536;
  else if (off < 262144) s = pw  + off - 196608;
  else if (off < 524288) s = f1  + off - 262144;
  else                   s = f2  + off - 524288;
  float4 v = *(const float4*)s;
  ushort4 u = {f2bf(v.x), f2bf(v.y), f2bf(v.z), f2bf(v.w)};
  *(ushort4*)(o + off) = u;
}

// ---------------- CPE + norm1 fused ----------------
__global__ void k_cpe_ln(const float* __restrict__ x, const float* __restrict__ w,
                         const float* __restrict__ bias, const float* __restrict__ g,
                         const float* __restrict__ be, float* __restrict__ x1,
                         float* __restrict__ xn, bf16u* __restrict__ xnb){
  int t = threadIdx.x;
  int pix = blockIdx.x*4 + (t >> 6);
  int b = pix / NN, n = pix % NN;
  int hy = n / WW, wx = n % WW;
  int c0 = (t & 63) * 4;
  float wv[4][9];
  float acc[4];
#pragma unroll
  for (int cc = 0; cc < 4; cc++){
    acc[cc] = bias[c0+cc];
#pragma unroll
    for (int k = 0; k < 9; k++) wv[cc][k] = w[(c0+cc)*9 + k];
  }
  const float* xb = x + (size_t)b*NN*CC + c0;
#pragma unroll
  for (int kh = 0; kh < 3; kh++){
    int iy = hy + kh - 1;
    if (iy < 0 || iy >= HH) continue;
#pragma unroll
    for (int kw = 0; kw < 3; kw++){
      int ix = wx + kw - 1;
      if (ix < 0 || ix >= WW) continue;
      float4 v = *(const float4*)&xb[(size_t)(iy*WW+ix)*CC];
      int k = kh*3+kw;
      acc[0] += v.x*wv[0][k]; acc[1] += v.y*wv[1][k];
      acc[2] += v.z*wv[2][k]; acc[3] += v.w*wv[3][k];
    }
  }
  float4 cv = *(const float4*)&xb[(size_t)n*CC];
  float o0 = cv.x + acc[0], o1 = cv.y + acc[1];
  float o2 = cv.z + acc[2], o3 = cv.w + acc[3];
  float4 ov = {o0,o1,o2,o3};
  *(float4*)&x1[(size_t)pix*CC + c0] = ov;
  float s  = o0+o1+o2+o3;
  float s2 = o0*o0+o1*o1+o2*o2+o3*o3;
#pragma unroll
  for (int off = 32; off; off >>= 1){
    s  += __shfl_xor(s,  off);
    s2 += __shfl_xor(s2, off);
  }
  float mean = s * (1.f/CC);
  float var  = s2 * (1.f/CC) - mean*mean;
  float rstd = rsqrtf(var + EPS_LN);
  float4 gv = *(const float4*)&g[c0];
  float4 bv = *(const float4*)&be[c0];
  float y0 = (o0-mean)*rstd*gv.x + bv.x;
  float y1 = (o1-mean)*rstd*gv.y + bv.y;
  float y2 = (o2-mean)*rstd*gv.z + bv.z;
  float y3 = (o3-mean)*rstd*gv.w + bv.w;
  float4 yv = {y0,y1,y2,y3};
  *(float4*)&xn[(size_t)pix*CC + c0] = yv;
  ushort4 yb = {f2bf_r(y0), f2bf_r(y1), f2bf_r(y2), f2bf_r(y3)};
  *(ushort4*)&xnb[(size_t)pix*CC + c0] = yb;
}

// ---------------- LayerNorm f32 -> bf16 ----------------
__global__ void k_ln_bf16(const float* __restrict__ X, const float* __restrict__ g,
                          const float* __restrict__ be, bf16u* __restrict__ Y){
  int row = blockIdx.x;
  int t = threadIdx.x;
  float v = X[(size_t)row*CC + t];
  float s = v, s2 = v*v;
#pragma unroll
  for (int off = 32; off; off >>= 1){
    s  += __shfl_down(s,  off);
    s2 += __shfl_down(s2, off);
  }
  __shared__ float red[10];
  int wv_ = t >> 6, ln = t & 63;
  if (ln == 0){ red[wv_] = s; red[4+wv_] = s2; }
  __syncthreads();
  if (t == 0){
    float S  = red[0]+red[1]+red[2]+red[3];
    float S2 = red[4]+red[5]+red[6]+red[7];
    float mean = S * (1.f/CC);
    float var  = S2 * (1.f/CC) - mean*mean;
    red[8] = mean; red[9] = rsqrtf(var + EPS_LN);
  }
  __syncthreads();
  float mean = red[8], rstd = red[9];
  Y[(size_t)row*CC + t] = f2bf_r((v - mean) * rstd * g[t] + be[t]);
}

// ---------------- adaptive avg pool ----------------
__global__ void k_pool(const float* __restrict__ xn, float* __restrict__ praw){
  int bp = blockIdx.x;
  int b = bp / PP, p = bp % PP;
  int ps, pi;
  if (p < 144)      { ps = 12; pi = p; }
  else if (p < 400) { ps = 16; pi = p - 144; }
  else if (p < 800) { ps = 20; pi = p - 400; }
  else              { ps = 24; pi = p - 800; }
  int oi = pi / ps, oj = pi % ps;
  int si = oi*HH/ps, ei = ((oi+1)*HH + ps - 1)/ps;
  int sj = oj*WW/ps, ej = ((oj+1)*WW + ps - 1)/ps;
  int c = threadIdx.x;
  const float* xb = xn + (size_t)b*NN*CC + c;
  float acc = 0.f;
  for (int i = si; i < ei; i++)
    for (int j = sj; j < ej; j++)
      acc += xb[(size_t)(i*WW+j)*CC];
  praw[(size_t)bp*CC + c] = acc / (float)((ei-si)*(ej-sj));
}

// ---------------- pool-dwconv + attn-norm fused -> bf16 ----------------
__global__ void k_pooldw_ln(const float* __restrict__ praw,
    const float* w0, const float* b0, const float* w1, const float* b1,
    const float* w2, const float* b2, const float* w3, const float* b3,
    const float* __restrict__ g, const float* __restrict__ be,
    bf16u* __restrict__ pools){
  int bp = blockIdx.x;
  int b = bp / PP, p = bp % PP;
  int ps, pi, off; const float *w, *bi;
  if (p < 144)      { ps=12; pi=p;     off=0;   w=w0; bi=b0; }
  else if (p < 400) { ps=16; pi=p-144; off=144; w=w1; bi=b1; }
  else if (p < 800) { ps=20; pi=p-400; off=400; w=w2; bi=b2; }
  else              { ps=24; pi=p-800; off=800; w=w3; bi=b3; }
  int oi = pi/ps, oj = pi%ps;
  int c = threadIdx.x;
  const float* base = praw + (size_t)(b*PP + off)*CC + c;
  float acc = bi[c];
#pragma unroll
  for (int kh = 0; kh < 3; kh++){
    int ii = oi + kh - 1; if (ii < 0 || ii >= ps) continue;
#pragma unroll
    for (int kw = 0; kw < 3; kw++){
      int jj = oj + kw - 1; if (jj < 0 || jj >= ps) continue;
      acc += base[(size_t)(ii*ps+jj)*CC] * w[c*9 + kh*3 + kw];
    }
  }
  float v = base[(size_t)(oi*ps+oj)*CC] + acc;
  float s = v, s2 = v*v;
#pragma unroll
  for (int o2_ = 32; o2_; o2_ >>= 1){
    s  += __shfl_down(s,  o2_);
    s2 += __shfl_down(s2, o2_);
  }
  __shared__ float red[10];
  int wv_ = c >> 6, ln = c & 63;
  if (ln == 0){ red[wv_] = s; red[4+wv_] = s2; }
  __syncthreads();
  if (c == 0){
    float S  = red[0]+red[1]+red[2]+red[3];
    float S2 = red[4]+red[5]+red[6]+red[7];
    float mean = S * (1.f/CC);
    float var  = S2 * (1.f/CC) - mean*mean;
    red[8] = mean; red[9] = rsqrtf(var + EPS_LN);
  }
  __syncthreads();
  float mean = red[8], rstd = red[9];
  pools[(size_t)bp*CC + c] = f2bf_r((v - mean) * rstd * g[c] + be[c]);
}

// ===== MFMA GEMM, bf16: Out = act(oscale*(A @ W^T) + bias) (+Res); NT = 128 or 64 =====
// VT_OUT: cols >= CC are the V-half of the kv projection -> written transposed to
// vtout[b][col-CC][p] (fuses the old k_vt kernel into the epilogue).
#define GST 40
template<int NT, bool OUT_BF16, bool HAS_BIAS, bool DO_GELU, bool HAS_RES, bool VT_OUT>
__global__ __launch_bounds__(256) void k_gemm_mfma(const bf16u* __restrict__ A,
                       const bf16u* __restrict__ Wt,
                       const float* __restrict__ bias, void* Outp,
                       const float* Res, bf16u* __restrict__ vtout,
                       int M, int Nout, int K, float oscale){
  constexpr int NW = (NT == 128) ? 4 : 2;
  __shared__ bf16u Ash[128*GST];
  __shared__ bf16u Bsh[NT*GST];
  int t = threadIdx.x;
  int wave = t >> 6, lane = t & 63, quad = lane >> 4, l16 = lane & 15;
  int m0 = blockIdx.y * 128, n0 = blockIdx.x * NT;
  int wm = (wave >> 1) * 64;
  int wn = (wave & 1) * (NT/2);
  int srow = t >> 1, scol = (t & 1) * 16;
  f32x4 zero = {0.f,0.f,0.f,0.f};
  f32x4 acc[4][NW];
#pragma unroll
  for (int i = 0; i < 4; i++)
#pragma unroll
    for (int j = 0; j < NW; j++) acc[i][j] = zero;
  for (int k0 = 0; k0 < K; k0 += 32){
    __syncthreads();
    {
      const bf16u* ap = A + (size_t)(m0+srow)*K + k0 + scol;
      uint4 u = *(const uint4*)ap;
      uint4 v = *(const uint4*)(ap+8);
      *(uint4*)&Ash[srow*GST + scol]     = u;
      *(uint4*)&Ash[srow*GST + scol + 8] = v;
    }
    if constexpr (NT == 128){
      const bf16u* bp = Wt + (size_t)(n0+srow)*K + k0 + scol;
      uint4 u = *(const uint4*)bp;
      uint4 v = *(const uint4*)(bp+8);
      *(uint4*)&Bsh[srow*GST + scol]     = u;
      *(uint4*)&Bsh[srow*GST + scol + 8] = v;
    } else {
      int br = t >> 2, bc = (t & 3) * 8;
      const bf16u* bp = Wt + (size_t)(n0+br)*K + k0 + bc;
      uint4 u = *(const uint4*)bp;
      *(uint4*)&Bsh[br*GST + bc] = u;
    }
    __syncthreads();
    short8 af[4], bfr[NW];
#pragma unroll
    for (int mi = 0; mi < 4; mi++)
      af[mi] = *(const short8*)&Ash[(wm + mi*16 + l16)*GST + quad*8];
#pragma unroll
    for (int ni = 0; ni < NW; ni++)
      bfr[ni] = *(const short8*)&Bsh[(wn + ni*16 + l16)*GST + quad*8];
#pragma unroll
    for (int mi = 0; mi < 4; mi++)
#pragma unroll
      for (int ni = 0; ni < NW; ni++)
        acc[mi][ni] = __builtin_amdgcn_mfma_f32_16x16x32_bf16(af[mi], bfr[ni], acc[mi][ni], 0,0,0);
  }
#pragma unroll
  for (int mi = 0; mi < 4; mi++){
#pragma unroll
    for (int r = 0; r < 4; r++){
      int row = m0 + wm + mi*16 + quad*4 + r;
#pragma unroll
      for (int ni = 0; ni < NW; ni++){
        int col = n0 + wn + ni*16 + l16;
        float v = acc[mi][ni][r] * oscale;
        if constexpr (HAS_BIAS) v += bias[col];
        if constexpr (DO_GELU)  v = 0.5f*v*(1.f + erff(v*0.70710678118654752f));
        if constexpr (HAS_RES)  v += Res[(size_t)row*Nout + col];
        if constexpr (VT_OUT){
          if (col < CC){
            ((bf16u*)Outp)[(size_t)row*Nout + col] = f2bf_r(v);
          } else {
            int bb = row / PP, pp = row - bb*PP;
            vtout[((size_t)(bb*CC + (col - CC)))*PPAD + pp] = f2bf_r(v);
          }
        } else if constexpr (OUT_BF16){
          ((bf16u*)Outp)[(size_t)row*Nout + col] = f2bf_r(v);
        } else {
          ((float*)Outp)[(size_t)row*Nout + col] = v;
        }
      }
    }
  }
}

// ============ MFMA flash attention: 128 q x 2 heads per block, 64-key chunks ============
// Each wave owns two 16-q tiles; K/V fragments loaded from LDS into registers ONCE per
// chunk and reused across both q-tiles (halves LDS traffic per unit work). S^T
// orientation (A=K, B=Q): b64 P writes, same-wave A-frag read-back (no barrier).
// Tail q-block (qt=24) has only 64 q (has2=false). Tail key chunk masks keys >= PP
// by skipping score-blocks 2,3 and kc=1 (1344+32 == PP).
#define KST 72
#define VST 72
#define PST 72
__global__ __launch_bounds__(256, 3) void k_attn_mfma(const bf16u* __restrict__ q,
                       const bf16u* __restrict__ kvb, const bf16u* __restrict__ vt,
                       bf16u* __restrict__ out){
  __shared__ bf16u Ksh[64*KST];          // [key][64 dims (2 heads)]
  __shared__ bf16u Vsh[64*VST];          // [d (2 heads x 32)][64 keys]
  __shared__ bf16u Psh[4][2][16*PST];    // [wave][head][q][64 keys]
  int t = threadIdx.x;
  int wave = t >> 6, lane = t & 63, quad = lane >> 4, l16 = lane & 15;
  int bid = blockIdx.x;
  int qt = bid % 25;
  int hp = (bid / 25) % (NHEAD/2);
  int b  = bid / (25*(NHEAD/2));
  int q0 = qt*128;
  bool has2 = (q0 + 64 < NN);
  short8 qf[2][2];
#pragma unroll
  for (int j = 0; j < 2; j++){
    const bf16u* qp = q + (size_t)(b*NN + q0 + j*64 + wave*16 + l16)*CC + hp*64 + quad*8;
    qf[j][0] = *(const short8*)qp;
    qf[j][1] = *(const short8*)(qp + HD);
  }
  f32x4 zero = {0.f,0.f,0.f,0.f};
  f32x4 o[2][2][2];
#pragma unroll
  for (int j = 0; j < 2; j++)
#pragma unroll
    for (int h = 0; h < 2; h++){ o[j][h][0] = zero; o[j][h][1] = zero; }
  float ls[2][2] = {{0.f,0.f},{0.f,0.f}};
  int sr = t >> 2, sc = (t & 3) * 16;
  const bf16u* ksrc = kvb + (size_t)(b*PP + sr)*(2*CC) + hp*64 + sc;
  const bf16u* vsrc = vt  + (size_t)(b*CC + hp*64 + sr)*PPAD + sc;
  uint4 ka = *(const uint4*)ksrc, kb = *(const uint4*)(ksrc+8);
  uint4 va = *(const uint4*)vsrc, vb = *(const uint4*)(vsrc+8);

#define DO_BLK(j_, h_, blk_, P_) { \
    f32x4 s = __builtin_amdgcn_mfma_f32_16x16x32_bf16(kf[blk_][h_], qf[j_][h_], zero, 0,0,0); \
    float ea = exp2f(s[0]), eb = exp2f(s[1]), ec = exp2f(s[2]), ed = exp2f(s[3]); \
    ls[j_][h_] += (ea+eb)+(ec+ed); \
    ushort4 pk = {f2bf_r(ea), f2bf_r(eb), f2bf_r(ec), f2bf_r(ed)}; \
    *(ushort4*)&P_[l16*PST + blk_*16 + quad*4] = pk; }

#define DO_PV(j_, h_, kc_, P_) { \
    short8 pf = *(const short8*)&P_[l16*PST + kc_*32 + quad*8]; \
    o[j_][h_][0] = __builtin_amdgcn_mfma_f32_16x16x32_bf16(pf, vf[kc_][h_*2+0], o[j_][h_][0], 0,0,0); \
    o[j_][h_][1] = __builtin_amdgcn_mfma_f32_16x16x32_bf16(pf, vf[kc_][h_*2+1], o[j_][h_][1], 0,0,0); }

  for (int ch = 0; ch < PPAD/64; ch++){
    __syncthreads();
    *(uint4*)&Ksh[sr*KST + sc]     = ka;
    *(uint4*)&Ksh[sr*KST + sc + 8] = kb;
    *(uint4*)&Vsh[sr*VST + sc]     = va;
    *(uint4*)&Vsh[sr*VST + sc + 8] = vb;
    if (ch < PPAD/64 - 1){
      ksrc += (size_t)64*(2*CC); vsrc += 64;
      ka = *(const uint4*)ksrc; kb = *(const uint4*)(ksrc+8);
      va = *(const uint4*)vsrc; vb = *(const uint4*)(vsrc+8);
    }
    __syncthreads();
    short8 kf[4][2], vf[2][4];
#pragma unroll
    for (int blk = 0; blk < 4; blk++){
      kf[blk][0] = *(const short8*)&Ksh[(blk*16 + l16)*KST +      quad*8];
      kf[blk][1] = *(const short8*)&Ksh[(blk*16 + l16)*KST + 32 + quad*8];
    }
#pragma unroll
    for (int kc = 0; kc < 2; kc++)
#pragma unroll
      for (int dj = 0; dj < 4; dj++)
        vf[kc][dj] = *(const short8*)&Vsh[(dj*16 + l16)*VST + kc*32 + quad*8];
    if (ch < PPAD/64 - 1){
#pragma unroll
      for (int j = 0; j < 2; j++){
        if (j && !has2) continue;
#pragma unroll
        for (int h = 0; h < 2; h++){
          bf16u* P = &Psh[wave][h][0];
          DO_BLK(j, h, 0, P) DO_BLK(j, h, 1, P) DO_BLK(j, h, 2, P) DO_BLK(j, h, 3, P)
          DO_PV(j, h, 0, P) DO_PV(j, h, 1, P)
        }
      }
    } else {
#pragma unroll
      for (int j = 0; j < 2; j++){
        if (j && !has2) continue;
#pragma unroll
        for (int h = 0; h < 2; h++){
          bf16u* P = &Psh[wave][h][0];
          DO_BLK(j, h, 0, P) DO_BLK(j, h, 1, P)
          DO_PV(j, h, 0, P)
        }
      }
    }
  }
#undef DO_BLK
#undef DO_PV
#pragma unroll
  for (int j = 0; j < 2; j++){
    if (j && !has2) continue;
#pragma unroll
    for (int h = 0; h < 2; h++){
      float l = ls[j][h];
      l += __shfl_xor(l, 16); l += __shfl_xor(l, 32);
#pragma unroll
      for (int r = 0; r < 4; r++){
        int qq = quad*4 + r;
        float inv = 1.f / __shfl(l, qq);
        size_t base = (size_t)(b*NN + q0 + j*64 + wave*16 + qq)*CC + hp*64 + h*32;
        out[base + l16     ] = f2bf_r(o[j][h][0][r]*inv);
        out[base + 16 + l16] = f2bf_r(o[j][h][1][r]*inv);
      }
    }
  }
}

// ---------------- h2 = h + dwconv3x3(h) + bias (hid=1024, bf16) ----------------
__global__ void k_dwh(const bf16u* __restrict__ h, const float* __restrict__ w,
                      const float* __restrict__ bias, bf16u* __restrict__ h2){
  int pix = blockIdx.x;
  int b = pix / NN, n = pix % NN;
  int hy = n / WW, wx = n % WW;
  int c0 = threadIdx.x * 4;
  float wv[4][9];
  float acc[4];
#pragma unroll
  for (int cc = 0; cc < 4; cc++){
    acc[cc] = bias[c0+cc];
#pragma unroll
    for (int k = 0; k < 9; k++) wv[cc][k] = w[(c0+cc)*9 + k];
  }
  const bf16u* hb = h + (size_t)b*NN*HIDN + c0;
#pragma unroll
  for (int kh = 0; kh < 3; kh++){
    int iy = hy + kh - 1; if (iy < 0 || iy >= HH) continue;
#pragma unroll
    for (int kw = 0; kw < 3; kw++){
      int ix = wx + kw - 1; if (ix < 0 || ix >= WW) continue;
      ushort4 hv = *(const ushort4*)&hb[(size_t)(iy*WW+ix)*HIDN];
      int k = kh*3+kw;
      acc[0] += bf2f(hv.x)*wv[0][k]; acc[1] += bf2f(hv.y)*wv[1][k];
      acc[2] += bf2f(hv.z)*wv[2][k]; acc[3] += bf2f(hv.w)*wv[3][k];
    }
  }
  ushort4 cv = *(const ushort4*)&hb[(size_t)n*HIDN];
  ushort4 o;
  o.x = f2bf_r(bf2f(cv.x) + acc[0]); o.y = f2bf_r(bf2f(cv.y) + acc[1]);
  o.z = f2bf_r(bf2f(cv.z) + acc[2]); o.w = f2bf_r(bf2f(cv.w) + acc[3]);
  *(ushort4*)&h2[(size_t)pix*HIDN + c0] = o;
}

extern "C" void kernel_launch(void* const* d_in, const int* in_sizes, int n_in,
                              void* d_out, int out_size, void* d_ws, size_t ws_size,
                              hipStream_t stream){
  const float* x      = (const float*)d_in[0];
  const float* cpe_w  = (const float*)d_in[1];
  const float* cpe_b  = (const float*)d_in[2];
  const float* n1w    = (const float*)d_in[3];
  const float* n1b    = (const float*)d_in[4];
  const float* q_w    = (const float*)d_in[5];
  const float* kv_w   = (const float*)d_in[6];
  const float* anw    = (const float*)d_in[7];
  const float* anb    = (const float*)d_in[8];
  const float* proj_w = (const float*)d_in[9];
  const float* proj_b = (const float*)d_in[10];
  const float* n2w    = (const float*)d_in[11];
  const float* n2b    = (const float*)d_in[12];
  const float* fc1_w  = (const float*)d_in[13];
  const float* fc1_b  = (const float*)d_in[14];
  const float* irb_w  = (const float*)d_in[15];
  const float* irb_b  = (const float*)d_in[16];
  const float* fc2_w  = (const float*)d_in[17];
  const float* fc2_b  = (const float*)d_in[18];
  const float* dw0    = (const float*)d_in[21];
  const float* db0    = (const float*)d_in[22];
  const float* dw1    = (const float*)d_in[23];
  const float* db1    = (const float*)d_in[24];
  const float* dw2    = (const float*)d_in[25];
  const float* db2    = (const float*)d_in[26];
  const float* dw3    = (const float*)d_in[27];
  const float* db3    = (const float*)d_in[28];

  const size_t BNC = (size_t)BQ*NN*CC;
  const size_t BPC = (size_t)BQ*PP*CC;
  const size_t BNH = (size_t)BQ*NN*HIDN;

  float* x1   = (float*)d_ws;
  bf16u* xnb  = (bf16u*)(x1 + BNC);
  bf16u* wbuf = xnb + BNC;
  bf16u* wq   = wbuf;
  bf16u* wkv  = wbuf + 65536;
  bf16u* wpj  = wbuf + 196608;
  bf16u* wf1  = wbuf + 262144;
  bf16u* wf2  = wbuf + 524288;
  float* A0   = (float*)(wbuf + 786432);
  float* xn   = A0;
  bf16u* qb   = (bf16u*)(xn + BNC);
  float* praw = (float*)(qb + BNC);
  bf16u* poolsb = (bf16u*)(praw + BPC);
  bf16u* kvb  = poolsb + BPC;                 // [BQ*PP][512] (V-half unused)
  bf16u* vtb  = kvb + (size_t)BQ*PP*2*CC;     // [BQ*256][PPAD]
  bf16u* hbuf = (bf16u*)A0;                   // phase-2 overlay
  bf16u* h2buf = hbuf + BNH;

  // 0. weights -> bf16
  k_wconv<<<768, 256, 0, stream>>>(q_w, kv_w, proj_w, fc1_w, fc2_w, wbuf);
  // 1. CPE + residual + norm1
  k_cpe_ln<<<BQ*NN/4, 256, 0, stream>>>(x, cpe_w, cpe_b, n1w, n1b, x1, xn, xnb);
  // 2. q projection -> bf16 (pre-scaled), NT=64
  k_gemm_mfma<64,true,false,false,false,false><<<dim3(CC/64, BQ*NN/128), 256, 0, stream>>>(
      xnb, wq, nullptr, qb, nullptr, nullptr, BQ*NN, CC, CC, QSCALE_LOG2E);
  // 3. pyramid pooling
  k_pool<<<BQ*PP, 256, 0, stream>>>(xn, praw);
  // 4. pool dwconv + attn-norm -> bf16
  k_pooldw_ln<<<BQ*PP, 256, 0, stream>>>(praw, dw0,db0, dw1,db1, dw2,db2, dw3,db3,
                                         anw, anb, poolsb);
  // 5. kv projection -> bf16, NT=64; V-half written transposed to vtb in epilogue
  k_gemm_mfma<64,true,false,false,false,true><<<dim3(2*CC/64, BQ*PP/128), 256, 0, stream>>>(
      poolsb, wkv, nullptr, kvb, nullptr, vtb, BQ*PP, 2*CC, CC, 1.0f);
  // 6. MFMA attention, 128 q/block (in-place: qb becomes attn output)
  k_attn_mfma<<<BQ*(NHEAD/2)*25, 256, 0, stream>>>(qb, kvb, vtb, qb);
  // 7. proj + bias + residual -> x1, NT=64
  k_gemm_mfma<64,false,true,false,true,false><<<dim3(CC/64, BQ*NN/128), 256, 0, stream>>>(
      qb, wpj, proj_b, x1, x1, nullptr, BQ*NN, CC, CC, 1.0f);
  // 8. norm2 -> bf16
  k_ln_bf16<<<BQ*NN, 256, 0, stream>>>(x1, n2w, n2b, xnb);
  // 9. fc1 + bias + gelu -> hbuf (bf16), NT=128
  k_gemm_mfma<128,true,true,true,false,false><<<dim3(HIDN/128, BQ*NN/128), 256, 0, stream>>>(
      xnb, wf1, fc1_b, hbuf, nullptr, nullptr, BQ*NN, HIDN, CC, 1.0f);
  // 10. h2 = h + dwconv(h)
  k_dwh<<<BQ*NN, 256, 0, stream>>>(hbuf, irb_w, irb_b, h2buf);
  // 11. fc2 + bias + residual -> d_out (f32), NT=64
  k_gemm_mfma<64,false,true,false,true,false><<<dim3(CC/64, BQ*NN/128), 256, 0, stream>>>(
      h2buf, wf2, fc2_b, d_out, x1, nullptr, BQ*NN, CC, HIDN, 1.0f);
}

// Round 11
// 417.463 us; speedup vs baseline: 1.2148x; 1.2148x over previous
//
#include <hip/hip_runtime.h>
#include <hip/hip_bf16.h>

#define BQ 4
#define HH 56
#define WW 56
#define NN (HH*WW)      // 3136
#define CC 256
#define NHEAD 8
#define HD 32
#define PP 1376
#define PPAD 1408       // 22 * 64
#define HIDN 1024
#define EPS_LN 1e-5f
// ATT_SCALE * log2(e): scores from QK^T come out ready for exp2
#define QSCALE_LOG2E 0.25503484f

typedef unsigned short bf16u;
typedef __attribute__((ext_vector_type(8))) short short8;
typedef __attribute__((ext_vector_type(4))) float f32x4;

__device__ __forceinline__ float bf2f(bf16u u){
  union { unsigned int i; float f; } v; v.i = ((unsigned int)u) << 16; return v.f;
}
__device__ __forceinline__ bf16u f2bf(float f){
  unsigned int x = __float_as_uint(f);
  x += 0x7fffu + ((x >> 16) & 1u);
  return (bf16u)(x >> 16);
}
// cheap half-up round (2 ops) for hot paths
__device__ __forceinline__ bf16u f2bf_r(float f){
  return (bf16u)((__float_as_uint(f) + 0x8000u) >> 16);
}

// ---------------- weights -> bf16, once per launch ----------------
__global__ void k_wconv(const float* __restrict__ qw, const float* __restrict__ kvw,
                        const float* __restrict__ pw, const float* __restrict__ f1,
                        const float* __restrict__ f2, bf16u* __restrict__ o){
  int off = (blockIdx.x*256 + threadIdx.x) * 4;
  const float* s;
  if (off < 65536)       s = qw  + off;
  else if (off < 196608) s = kvw + off - 65536;
  else if (off < 262144) s = pw  + off - 196608;
  else if (off < 524288) s = f1  + off - 262144;
  else                   s = f2  + off - 524288;
  float4 v = *(const float4*)s;
  ushort4 u = {f2bf(v.x), f2bf(v.y), f2bf(v.z), f2bf(v.w)};
  *(ushort4*)(o + off) = u;
}

// ---------------- CPE + norm1 fused ----------------
__global__ void k_cpe_ln(const float* __restrict__ x, const float* __restrict__ w,
                         const float* __restrict__ bias, const float* __restrict__ g,
                         const float* __restrict__ be, float* __restrict__ x1,
                         float* __restrict__ xn, bf16u* __restrict__ xnb){
  int t = threadIdx.x;
  int pix = blockIdx.x*4 + (t >> 6);
  int b = pix / NN, n = pix % NN;
  int hy = n / WW, wx = n % WW;
  int c0 = (t & 63) * 4;
  float wv[4][9];
  float acc[4];
#pragma unroll
  for (int cc = 0; cc < 4; cc++){
    acc[cc] = bias[c0+cc];
#pragma unroll
    for (int k = 0; k < 9; k++) wv[cc][k] = w[(c0+cc)*9 + k];
  }
  const float* xb = x + (size_t)b*NN*CC + c0;
#pragma unroll
  for (int kh = 0; kh < 3; kh++){
    int iy = hy + kh - 1;
    if (iy < 0 || iy >= HH) continue;
#pragma unroll
    for (int kw = 0; kw < 3; kw++){
      int ix = wx + kw - 1;
      if (ix < 0 || ix >= WW) continue;
      float4 v = *(const float4*)&xb[(size_t)(iy*WW+ix)*CC];
      int k = kh*3+kw;
      acc[0] += v.x*wv[0][k]; acc[1] += v.y*wv[1][k];
      acc[2] += v.z*wv[2][k]; acc[3] += v.w*wv[3][k];
    }
  }
  float4 cv = *(const float4*)&xb[(size_t)n*CC];
  float o0 = cv.x + acc[0], o1 = cv.y + acc[1];
  float o2 = cv.z + acc[2], o3 = cv.w + acc[3];
  float4 ov = {o0,o1,o2,o3};
  *(float4*)&x1[(size_t)pix*CC + c0] = ov;
  float s  = o0+o1+o2+o3;
  float s2 = o0*o0+o1*o1+o2*o2+o3*o3;
#pragma unroll
  for (int off = 32; off; off >>= 1){
    s  += __shfl_xor(s,  off);
    s2 += __shfl_xor(s2, off);
  }
  float mean = s * (1.f/CC);
  float var  = s2 * (1.f/CC) - mean*mean;
  float rstd = rsqrtf(var + EPS_LN);
  float4 gv = *(const float4*)&g[c0];
  float4 bv = *(const float4*)&be[c0];
  float y0 = (o0-mean)*rstd*gv.x + bv.x;
  float y1 = (o1-mean)*rstd*gv.y + bv.y;
  float y2 = (o2-mean)*rstd*gv.z + bv.z;
  float y3 = (o3-mean)*rstd*gv.w + bv.w;
  float4 yv = {y0,y1,y2,y3};
  *(float4*)&xn[(size_t)pix*CC + c0] = yv;
  ushort4 yb = {f2bf_r(y0), f2bf_r(y1), f2bf_r(y2), f2bf_r(y3)};
  *(ushort4*)&xnb[(size_t)pix*CC + c0] = yb;
}

// ---------------- LayerNorm f32 -> bf16 ----------------
__global__ void k_ln_bf16(const float* __restrict__ X, const float* __restrict__ g,
                          const float* __restrict__ be, bf16u* __restrict__ Y){
  int row = blockIdx.x;
  int t = threadIdx.x;
  float v = X[(size_t)row*CC + t];
  float s = v, s2 = v*v;
#pragma unroll
  for (int off = 32; off; off >>= 1){
    s  += __shfl_down(s,  off);
    s2 += __shfl_down(s2, off);
  }
  __shared__ float red[10];
  int wv_ = t >> 6, ln = t & 63;
  if (ln == 0){ red[wv_] = s; red[4+wv_] = s2; }
  __syncthreads();
  if (t == 0){
    float S  = red[0]+red[1]+red[2]+red[3];
    float S2 = red[4]+red[5]+red[6]+red[7];
    float mean = S * (1.f/CC);
    float var  = S2 * (1.f/CC) - mean*mean;
    red[8] = mean; red[9] = rsqrtf(var + EPS_LN);
  }
  __syncthreads();
  float mean = red[8], rstd = red[9];
  Y[(size_t)row*CC + t] = f2bf_r((v - mean) * rstd * g[t] + be[t]);
}

// ---------------- adaptive avg pool ----------------
__global__ void k_pool(const float* __restrict__ xn, float* __restrict__ praw){
  int bp = blockIdx.x;
  int b = bp / PP, p = bp % PP;
  int ps, pi;
  if (p < 144)      { ps = 12; pi = p; }
  else if (p < 400) { ps = 16; pi = p - 144; }
  else if (p < 800) { ps = 20; pi = p - 400; }
  else              { ps = 24; pi = p - 800; }
  int oi = pi / ps, oj = pi % ps;
  int si = oi*HH/ps, ei = ((oi+1)*HH + ps - 1)/ps;
  int sj = oj*WW/ps, ej = ((oj+1)*WW + ps - 1)/ps;
  int c = threadIdx.x;
  const float* xb = xn + (size_t)b*NN*CC + c;
  float acc = 0.f;
  for (int i = si; i < ei; i++)
    for (int j = sj; j < ej; j++)
      acc += xb[(size_t)(i*WW+j)*CC];
  praw[(size_t)bp*CC + c] = acc / (float)((ei-si)*(ej-sj));
}

// ---------------- pool-dwconv + attn-norm fused -> bf16 ----------------
__global__ void k_pooldw_ln(const float* __restrict__ praw,
    const float* w0, const float* b0, const float* w1, const float* b1,
    const float* w2, const float* b2, const float* w3, const float* b3,
    const float* __restrict__ g, const float* __restrict__ be,
    bf16u* __restrict__ pools){
  int bp = blockIdx.x;
  int b = bp / PP, p = bp % PP;
  int ps, pi, off; const float *w, *bi;
  if (p < 144)      { ps=12; pi=p;     off=0;   w=w0; bi=b0; }
  else if (p < 400) { ps=16; pi=p-144; off=144; w=w1; bi=b1; }
  else if (p < 800) { ps=20; pi=p-400; off=400; w=w2; bi=b2; }
  else              { ps=24; pi=p-800; off=800; w=w3; bi=b3; }
  int oi = pi/ps, oj = pi%ps;
  int c = threadIdx.x;
  const float* base = praw + (size_t)(b*PP + off)*CC + c;
  float acc = bi[c];
#pragma unroll
  for (int kh = 0; kh < 3; kh++){
    int ii = oi + kh - 1; if (ii < 0 || ii >= ps) continue;
#pragma unroll
    for (int kw = 0; kw < 3; kw++){
      int jj = oj + kw - 1; if (jj < 0 || jj >= ps) continue;
      acc += base[(size_t)(ii*ps+jj)*CC] * w[c*9 + kh*3 + kw];
    }
  }
  float v = base[(size_t)(oi*ps+oj)*CC] + acc;
  float s = v, s2 = v*v;
#pragma unroll
  for (int o2_ = 32; o2_; o2_ >>= 1){
    s  += __shfl_down(s,  o2_);
    s2 += __shfl_down(s2, o2_);
  }
  __shared__ float red[10];
  int wv_ = c >> 6, ln = c & 63;
  if (ln == 0){ red[wv_] = s; red[4+wv_] = s2; }
  __syncthreads();
  if (c == 0){
    float S  = red[0]+red[1]+red[2]+red[3];
    float S2 = red[4]+red[5]+red[6]+red[7];
    float mean = S * (1.f/CC);
    float var  = S2 * (1.f/CC) - mean*mean;
    red[8] = mean; red[9] = rsqrtf(var + EPS_LN);
  }
  __syncthreads();
  float mean = red[8], rstd = red[9];
  pools[(size_t)bp*CC + c] = f2bf_r((v - mean) * rstd * g[c] + be[c]);
}

// ===== MFMA GEMM, bf16: Out = act(oscale*(A @ W^T) + bias) (+Res); NT = 128 or 64 =====
// VT_OUT: cols >= CC are the V-half of the kv projection -> written transposed to
// vtout[b][col-CC][p] (k_vt fused into the epilogue).
#define GST 40
template<int NT, bool OUT_BF16, bool HAS_BIAS, bool DO_GELU, bool HAS_RES, bool VT_OUT>
__global__ __launch_bounds__(256) void k_gemm_mfma(const bf16u* __restrict__ A,
                       const bf16u* __restrict__ Wt,
                       const float* __restrict__ bias, void* Outp,
                       const float* Res, bf16u* __restrict__ vtout,
                       int M, int Nout, int K, float oscale){
  constexpr int NW = (NT == 128) ? 4 : 2;
  __shared__ bf16u Ash[128*GST];
  __shared__ bf16u Bsh[NT*GST];
  int t = threadIdx.x;
  int wave = t >> 6, lane = t & 63, quad = lane >> 4, l16 = lane & 15;
  int m0 = blockIdx.y * 128, n0 = blockIdx.x * NT;
  int wm = (wave >> 1) * 64;
  int wn = (wave & 1) * (NT/2);
  int srow = t >> 1, scol = (t & 1) * 16;
  f32x4 zero = {0.f,0.f,0.f,0.f};
  f32x4 acc[4][NW];
#pragma unroll
  for (int i = 0; i < 4; i++)
#pragma unroll
    for (int j = 0; j < NW; j++) acc[i][j] = zero;
  for (int k0 = 0; k0 < K; k0 += 32){
    __syncthreads();
    {
      const bf16u* ap = A + (size_t)(m0+srow)*K + k0 + scol;
      uint4 u = *(const uint4*)ap;
      uint4 v = *(const uint4*)(ap+8);
      *(uint4*)&Ash[srow*GST + scol]     = u;
      *(uint4*)&Ash[srow*GST + scol + 8] = v;
    }
    if constexpr (NT == 128){
      const bf16u* bp = Wt + (size_t)(n0+srow)*K + k0 + scol;
      uint4 u = *(const uint4*)bp;
      uint4 v = *(const uint4*)(bp+8);
      *(uint4*)&Bsh[srow*GST + scol]     = u;
      *(uint4*)&Bsh[srow*GST + scol + 8] = v;
    } else {
      int br = t >> 2, bc = (t & 3) * 8;
      const bf16u* bp = Wt + (size_t)(n0+br)*K + k0 + bc;
      uint4 u = *(const uint4*)bp;
      *(uint4*)&Bsh[br*GST + bc] = u;
    }
    __syncthreads();
    short8 af[4], bfr[NW];
#pragma unroll
    for (int mi = 0; mi < 4; mi++)
      af[mi] = *(const short8*)&Ash[(wm + mi*16 + l16)*GST + quad*8];
#pragma unroll
    for (int ni = 0; ni < NW; ni++)
      bfr[ni] = *(const short8*)&Bsh[(wn + ni*16 + l16)*GST + quad*8];
#pragma unroll
    for (int mi = 0; mi < 4; mi++)
#pragma unroll
      for (int ni = 0; ni < NW; ni++)
        acc[mi][ni] = __builtin_amdgcn_mfma_f32_16x16x32_bf16(af[mi], bfr[ni], acc[mi][ni], 0,0,0);
  }
#pragma unroll
  for (int mi = 0; mi < 4; mi++){
#pragma unroll
    for (int r = 0; r < 4; r++){
      int row = m0 + wm + mi*16 + quad*4 + r;
#pragma unroll
      for (int ni = 0; ni < NW; ni++){
        int col = n0 + wn + ni*16 + l16;
        float v = acc[mi][ni][r] * oscale;
        if constexpr (HAS_BIAS) v += bias[col];
        if constexpr (DO_GELU)  v = 0.5f*v*(1.f + erff(v*0.70710678118654752f));
        if constexpr (HAS_RES)  v += Res[(size_t)row*Nout + col];
        if constexpr (VT_OUT){
          if (col < CC){
            ((bf16u*)Outp)[(size_t)row*Nout + col] = f2bf_r(v);
          } else {
            int bb = row / PP, pp = row - bb*PP;
            vtout[((size_t)(bb*CC + (col - CC)))*PPAD + pp] = f2bf_r(v);
          }
        } else if constexpr (OUT_BF16){
          ((bf16u*)Outp)[(size_t)row*Nout + col] = f2bf_r(v);
        } else {
          ((float*)Outp)[(size_t)row*Nout + col] = v;
        }
      }
    }
  }
}

// ============ MFMA flash attention: 64 q x 2 heads per block, 64-key chunks ============
// R9 structure (inline frag loads, 64 VGPR) + double-buffered K/V LDS -> ONE barrier
// per chunk. Safety: compute of chunk i precedes writes of i+1 (program order); writes
// of i+2 reuse buffer (i&1) only after barrier i+1, which all waves pass only after
// finishing compute i. S^T orientation: b64 P writes, same-wave A-frag read (no barrier).
// Tail chunk masks keys >= PP by skipping score-blocks 2,3 / kc=1 (1344+32 == PP).
#define KST 72
#define VST 72
#define PST 40
__global__ __launch_bounds__(256) void k_attn_mfma(const bf16u* __restrict__ q,
                       const bf16u* __restrict__ kvb, const bf16u* __restrict__ vt,
                       bf16u* __restrict__ out){
  __shared__ bf16u Ksh[2][64*KST];       // [buf][key][64 dims (2 heads)]
  __shared__ bf16u Vsh[2][64*VST];       // [buf][d (2 heads x 32)][64 keys]
  __shared__ bf16u Psh[4][2][16*PST];    // [wave][head][q][64 keys]
  int t = threadIdx.x;
  int wave = t >> 6, lane = t & 63, quad = lane >> 4, l16 = lane & 15;
  int bid = blockIdx.x;
  int qt = bid % (NN/64);
  int hp = (bid / (NN/64)) % (NHEAD/2);
  int b  = bid / ((NN/64)*(NHEAD/2));
  int q0 = qt*64 + wave*16;
  const bf16u* qptr = q + (size_t)(b*NN + q0 + l16)*CC + hp*64 + quad*8;
  short8 qf0 = *(const short8*)qptr;
  short8 qf1 = *(const short8*)(qptr + HD);
  f32x4 zero = {0.f,0.f,0.f,0.f};
  f32x4 o00 = zero, o01 = zero, o10 = zero, o11 = zero;
  float ls0 = 0.f, ls1 = 0.f;
  int sr = t >> 2, sc = (t & 3) * 16;
  const bf16u* ksrc = kvb + (size_t)(b*PP + sr)*(2*CC) + hp*64 + sc;
  const bf16u* vsrc = vt  + (size_t)(b*CC + hp*64 + sr)*PPAD + sc;
  uint4 ka = *(const uint4*)ksrc, kb = *(const uint4*)(ksrc+8);
  uint4 va = *(const uint4*)vsrc, vb = *(const uint4*)(vsrc+8);

#define DO_BLK(blk) { \
    short8 kf0 = *(const short8*)&Kc[(blk*16 + l16)*KST + quad*8]; \
    short8 kf1 = *(const short8*)&Kc[(blk*16 + l16)*KST + 32 + quad*8]; \
    f32x4 s0 = __builtin_amdgcn_mfma_f32_16x16x32_bf16(kf0, qf0, zero, 0,0,0); \
    f32x4 s1 = __builtin_amdgcn_mfma_f32_16x16x32_bf16(kf1, qf1, zero, 0,0,0); \
    float e0a = exp2f(s0[0]), e0b = exp2f(s0[1]), e0c = exp2f(s0[2]), e0d = exp2f(s0[3]); \
    float e1a = exp2f(s1[0]), e1b = exp2f(s1[1]), e1c = exp2f(s1[2]), e1d = exp2f(s1[3]); \
    ls0 += (e0a+e0b)+(e0c+e0d); ls1 += (e1a+e1b)+(e1c+e1d); \
    ushort4 pa = {f2bf_r(e0a), f2bf_r(e0b), f2bf_r(e0c), f2bf_r(e0d)}; \
    ushort4 pb = {f2bf_r(e1a), f2bf_r(e1b), f2bf_r(e1c), f2bf_r(e1d)}; \
    *(ushort4*)&P0[l16*PST + blk*16 + quad*4] = pa; \
    *(ushort4*)&P1[l16*PST + blk*16 + quad*4] = pb; }

#define DO_PV(kc) { \
    short8 pf0 = *(const short8*)&P0[l16*PST + kc*32 + quad*8]; \
    short8 pf1 = *(const short8*)&P1[l16*PST + kc*32 + quad*8]; \
    short8 vf00 = *(const short8*)&Vc[(     l16)*VST + kc*32 + quad*8]; \
    short8 vf01 = *(const short8*)&Vc[(16 + l16)*VST + kc*32 + quad*8]; \
    short8 vf10 = *(const short8*)&Vc[(32 + l16)*VST + kc*32 + quad*8]; \
    short8 vf11 = *(const short8*)&Vc[(48 + l16)*VST + kc*32 + quad*8]; \
    o00 = __builtin_amdgcn_mfma_f32_16x16x32_bf16(pf0, vf00, o00, 0,0,0); \
    o01 = __builtin_amdgcn_mfma_f32_16x16x32_bf16(pf0, vf01, o01, 0,0,0); \
    o10 = __builtin_amdgcn_mfma_f32_16x16x32_bf16(pf1, vf10, o10, 0,0,0); \
    o11 = __builtin_amdgcn_mfma_f32_16x16x32_bf16(pf1, vf11, o11, 0,0,0); }

  for (int ch = 0; ch < PPAD/64; ch++){
    bf16u* Kc = &Ksh[ch & 1][0];
    bf16u* Vc = &Vsh[ch & 1][0];
    *(uint4*)&Kc[sr*KST + sc]     = ka;
    *(uint4*)&Kc[sr*KST + sc + 8] = kb;
    *(uint4*)&Vc[sr*VST + sc]     = va;
    *(uint4*)&Vc[sr*VST + sc + 8] = vb;
    if (ch < PPAD/64 - 1){
      ksrc += (size_t)64*(2*CC); vsrc += 64;
      ka = *(const uint4*)ksrc; kb = *(const uint4*)(ksrc+8);
      va = *(const uint4*)vsrc; vb = *(const uint4*)(vsrc+8);
    }
    __syncthreads();
    bf16u* P0 = &Psh[wave][0][0];
    bf16u* P1 = &Psh[wave][1][0];
    if (ch < PPAD/64 - 1){
      DO_BLK(0) DO_BLK(1) DO_BLK(2) DO_BLK(3)
      DO_PV(0) DO_PV(1)
    } else {
      // tail: keys 1344..1375 valid, 1376..1407 masked off entirely
      DO_BLK(0) DO_BLK(1)
      DO_PV(0)
    }
  }
#undef DO_BLK
#undef DO_PV
  ls0 += __shfl_xor(ls0, 16); ls0 += __shfl_xor(ls0, 32);
  ls1 += __shfl_xor(ls1, 16); ls1 += __shfl_xor(ls1, 32);
#pragma unroll
  for (int r = 0; r < 4; r++){
    int qq = quad*4 + r;
    float i0 = 1.f / __shfl(ls0, qq);
    float i1 = 1.f / __shfl(ls1, qq);
    size_t base = (size_t)(b*NN + q0 + qq)*CC + hp*64;
    out[base + l16     ] = f2bf_r(o00[r]*i0);
    out[base + 16 + l16] = f2bf_r(o01[r]*i0);
    out[base + 32 + l16] = f2bf_r(o10[r]*i1);
    out[base + 48 + l16] = f2bf_r(o11[r]*i1);
  }
}

// ---------------- h2 = h + dwconv3x3(h) + bias (hid=1024, bf16) ----------------
__global__ void k_dwh(const bf16u* __restrict__ h, const float* __restrict__ w,
                      const float* __restrict__ bias, bf16u* __restrict__ h2){
  int pix = blockIdx.x;
  int b = pix / NN, n = pix % NN;
  int hy = n / WW, wx = n % WW;
  int c0 = threadIdx.x * 4;
  float wv[4][9];
  float acc[4];
#pragma unroll
  for (int cc = 0; cc < 4; cc++){
    acc[cc] = bias[c0+cc];
#pragma unroll
    for (int k = 0; k < 9; k++) wv[cc][k] = w[(c0+cc)*9 + k];
  }
  const bf16u* hb = h + (size_t)b*NN*HIDN + c0;
#pragma unroll
  for (int kh = 0; kh < 3; kh++){
    int iy = hy + kh - 1; if (iy < 0 || iy >= HH) continue;
#pragma unroll
    for (int kw = 0; kw < 3; kw++){
      int ix = wx + kw - 1; if (ix < 0 || ix >= WW) continue;
      ushort4 hv = *(const ushort4*)&hb[(size_t)(iy*WW+ix)*HIDN];
      int k = kh*3+kw;
      acc[0] += bf2f(hv.x)*wv[0][k]; acc[1] += bf2f(hv.y)*wv[1][k];
      acc[2] += bf2f(hv.z)*wv[2][k]; acc[3] += bf2f(hv.w)*wv[3][k];
    }
  }
  ushort4 cv = *(const ushort4*)&hb[(size_t)n*HIDN];
  ushort4 o;
  o.x = f2bf_r(bf2f(cv.x) + acc[0]); o.y = f2bf_r(bf2f(cv.y) + acc[1]);
  o.z = f2bf_r(bf2f(cv.z) + acc[2]); o.w = f2bf_r(bf2f(cv.w) + acc[3]);
  *(ushort4*)&h2[(size_t)pix*HIDN + c0] = o;
}

extern "C" void kernel_launch(void* const* d_in, const int* in_sizes, int n_in,
                              void* d_out, int out_size, void* d_ws, size_t ws_size,
                              hipStream_t stream){
  const float* x      = (const float*)d_in[0];
  const float* cpe_w  = (const float*)d_in[1];
  const float* cpe_b  = (const float*)d_in[2];
  const float* n1w    = (const float*)d_in[3];
  const float* n1b    = (const float*)d_in[4];
  const float* q_w    = (const float*)d_in[5];
  const float* kv_w   = (const float*)d_in[6];
  const float* anw    = (const float*)d_in[7];
  const float* anb    = (const float*)d_in[8];
  const float* proj_w = (const float*)d_in[9];
  const float* proj_b = (const float*)d_in[10];
  const float* n2w    = (const float*)d_in[11];
  const float* n2b    = (const float*)d_in[12];
  const float* fc1_w  = (const float*)d_in[13];
  const float* fc1_b  = (const float*)d_in[14];
  const float* irb_w  = (const float*)d_in[15];
  const float* irb_b  = (const float*)d_in[16];
  const float* fc2_w  = (const float*)d_in[17];
  const float* fc2_b  = (const float*)d_in[18];
  const float* dw0    = (const float*)d_in[21];
  const float* db0    = (const float*)d_in[22];
  const float* dw1    = (const float*)d_in[23];
  const float* db1    = (const float*)d_in[24];
  const float* dw2    = (const float*)d_in[25];
  const float* db2    = (const float*)d_in[26];
  const float* dw3    = (const float*)d_in[27];
  const float* db3    = (const float*)d_in[28];

  const size_t BNC = (size_t)BQ*NN*CC;
  const size_t BPC = (size_t)BQ*PP*CC;
  const size_t BNH = (size_t)BQ*NN*HIDN;

  float* x1   = (float*)d_ws;
  bf16u* xnb  = (bf16u*)(x1 + BNC);
  bf16u* wbuf = xnb + BNC;
  bf16u* wq   = wbuf;
  bf16u* wkv  = wbuf + 65536;
  bf16u* wpj  = wbuf + 196608;
  bf16u* wf1  = wbuf + 262144;
  bf16u* wf2  = wbuf + 524288;
  float* A0   = (float*)(wbuf + 786432);
  float* xn   = A0;
  bf16u* qb   = (bf16u*)(xn + BNC);
  float* praw = (float*)(qb + BNC);
  bf16u* poolsb = (bf16u*)(praw + BPC);
  bf16u* kvb  = poolsb + BPC;                 // [BQ*PP][512] (V-half unused by attn)
  bf16u* vtb  = kvb + (size_t)BQ*PP*2*CC;     // [BQ*256][PPAD]
  bf16u* hbuf = (bf16u*)A0;                   // phase-2 overlay
  bf16u* h2buf = hbuf + BNH;

  // 0. weights -> bf16
  k_wconv<<<768, 256, 0, stream>>>(q_w, kv_w, proj_w, fc1_w, fc2_w, wbuf);
  // 1. CPE + residual + norm1
  k_cpe_ln<<<BQ*NN/4, 256, 0, stream>>>(x, cpe_w, cpe_b, n1w, n1b, x1, xn, xnb);
  // 2. q projection -> bf16 (pre-scaled), NT=64
  k_gemm_mfma<64,true,false,false,false,false><<<dim3(CC/64, BQ*NN/128), 256, 0, stream>>>(
      xnb, wq, nullptr, qb, nullptr, nullptr, BQ*NN, CC, CC, QSCALE_LOG2E);
  // 3. pyramid pooling
  k_pool<<<BQ*PP, 256, 0, stream>>>(xn, praw);
  // 4. pool dwconv + attn-norm -> bf16
  k_pooldw_ln<<<BQ*PP, 256, 0, stream>>>(praw, dw0,db0, dw1,db1, dw2,db2, dw3,db3,
                                         anw, anb, poolsb);
  // 5. kv projection -> bf16, NT=64; V-half written transposed to vtb in epilogue
  k_gemm_mfma<64,true,false,false,false,true><<<dim3(2*CC/64, BQ*PP/128), 256, 0, stream>>>(
      poolsb, wkv, nullptr, kvb, nullptr, vtb, BQ*PP, 2*CC, CC, 1.0f);
  // 6. MFMA attention, 64 q/block, double-buffered (in-place: qb becomes attn out)
  k_attn_mfma<<<BQ*(NHEAD/2)*(NN/64), 256, 0, stream>>>(qb, kvb, vtb, qb);
  // 7. proj + bias + residual -> x1, NT=64
  k_gemm_mfma<64,false,true,false,true,false><<<dim3(CC/64, BQ*NN/128), 256, 0, stream>>>(
      qb, wpj, proj_b, x1, x1, nullptr, BQ*NN, CC, CC, 1.0f);
  // 8. norm2 -> bf16
  k_ln_bf16<<<BQ*NN, 256, 0, stream>>>(x1, n2w, n2b, xnb);
  // 9. fc1 + bias + gelu -> hbuf (bf16), NT=128
  k_gemm_mfma<128,true,true,true,false,false><<<dim3(HIDN/128, BQ*NN/128), 256, 0, stream>>>(
      xnb, wf1, fc1_b, hbuf, nullptr, nullptr, BQ*NN, HIDN, CC, 1.0f);
  // 10. h2 = h + dwconv(h)
  k_dwh<<<BQ*NN, 256, 0, stream>>>(hbuf, irb_w, irb_b, h2buf);
  // 11. fc2 + bias + residual -> d_out (f32), NT=64
  k_gemm_mfma<64,false,true,false,true,false><<<dim3(CC/64, BQ*NN/128), 256, 0, stream>>>(
      h2buf, wf2, fc2_b, d_out, x1, nullptr, BQ*NN, CC, HIDN, 1.0f);
}

// Round 12
// 398.021 us; speedup vs baseline: 1.2741x; 1.0488x over previous
//
#include <hip/hip_runtime.h>
#include <hip/hip_bf16.h>

#define BQ 4
#define HH 56
#define WW 56
#define NN (HH*WW)      // 3136
#define CC 256
#define NHEAD 8
#define HD 32
#define PP 1376
#define PPAD 1408       // 22 * 64
#define HIDN 1024
#define EPS_LN 1e-5f
// ATT_SCALE * log2(e): scores from QK^T come out ready for exp2
#define QSCALE_LOG2E 0.25503484f

typedef unsigned short bf16u;
typedef __attribute__((ext_vector_type(8))) short short8;
typedef __attribute__((ext_vector_type(4))) float f32x4;

__device__ __forceinline__ float bf2f(bf16u u){
  union { unsigned int i; float f; } v; v.i = ((unsigned int)u) << 16; return v.f;
}
__device__ __forceinline__ bf16u f2bf(float f){
  unsigned int x = __float_as_uint(f);
  x += 0x7fffu + ((x >> 16) & 1u);
  return (bf16u)(x >> 16);
}
// cheap half-up round (2 ops) for hot paths
__device__ __forceinline__ bf16u f2bf_r(float f){
  return (bf16u)((__float_as_uint(f) + 0x8000u) >> 16);
}

// ---------------- fused init: blocks [0,768) convert weights; rest do CPE+norm1 ----------------
// CPE: x1 = x + dwconv3x3(x)+b (f32); xnb = LN(x1) (bf16). One wave per pixel.
__global__ void k_init(const float* __restrict__ qw, const float* __restrict__ kvw,
                       const float* __restrict__ pw, const float* __restrict__ f1,
                       const float* __restrict__ f2, bf16u* __restrict__ wo,
                       const float* __restrict__ x, const float* __restrict__ w,
                       const float* __restrict__ bias, const float* __restrict__ g,
                       const float* __restrict__ be, float* __restrict__ x1,
                       bf16u* __restrict__ xnb){
  if (blockIdx.x < 768){
    int off = (blockIdx.x*256 + threadIdx.x) * 4;
    const float* s;
    if (off < 65536)       s = qw  + off;
    else if (off < 196608) s = kvw + off - 65536;
    else if (off < 262144) s = pw  + off - 196608;
    else if (off < 524288) s = f1  + off - 262144;
    else                   s = f2  + off - 524288;
    float4 v = *(const float4*)s;
    ushort4 u = {f2bf(v.x), f2bf(v.y), f2bf(v.z), f2bf(v.w)};
    *(ushort4*)(wo + off) = u;
    return;
  }
  int t = threadIdx.x;
  int pix = (blockIdx.x - 768)*4 + (t >> 6);
  int b = pix / NN, n = pix % NN;
  int hy = n / WW, wx = n % WW;
  int c0 = (t & 63) * 4;
  float wv[4][9];
  float acc[4];
#pragma unroll
  for (int cc = 0; cc < 4; cc++){
    acc[cc] = bias[c0+cc];
#pragma unroll
    for (int k = 0; k < 9; k++) wv[cc][k] = w[(c0+cc)*9 + k];
  }
  const float* xb = x + (size_t)b*NN*CC + c0;
#pragma unroll
  for (int kh = 0; kh < 3; kh++){
    int iy = hy + kh - 1;
    if (iy < 0 || iy >= HH) continue;
#pragma unroll
    for (int kw = 0; kw < 3; kw++){
      int ix = wx + kw - 1;
      if (ix < 0 || ix >= WW) continue;
      float4 v = *(const float4*)&xb[(size_t)(iy*WW+ix)*CC];
      int k = kh*3+kw;
      acc[0] += v.x*wv[0][k]; acc[1] += v.y*wv[1][k];
      acc[2] += v.z*wv[2][k]; acc[3] += v.w*wv[3][k];
    }
  }
  float4 cv = *(const float4*)&xb[(size_t)n*CC];
  float o0 = cv.x + acc[0], o1 = cv.y + acc[1];
  float o2 = cv.z + acc[2], o3 = cv.w + acc[3];
  float4 ov = {o0,o1,o2,o3};
  *(float4*)&x1[(size_t)pix*CC + c0] = ov;
  float s  = o0+o1+o2+o3;
  float s2 = o0*o0+o1*o1+o2*o2+o3*o3;
#pragma unroll
  for (int off = 32; off; off >>= 1){
    s  += __shfl_xor(s,  off);
    s2 += __shfl_xor(s2, off);
  }
  float mean = s * (1.f/CC);
  float var  = s2 * (1.f/CC) - mean*mean;
  float rstd = rsqrtf(var + EPS_LN);
  float4 gv = *(const float4*)&g[c0];
  float4 bv = *(const float4*)&be[c0];
  float y0 = (o0-mean)*rstd*gv.x + bv.x;
  float y1 = (o1-mean)*rstd*gv.y + bv.y;
  float y2 = (o2-mean)*rstd*gv.z + bv.z;
  float y3 = (o3-mean)*rstd*gv.w + bv.w;
  ushort4 yb = {f2bf_r(y0), f2bf_r(y1), f2bf_r(y2), f2bf_r(y3)};
  *(ushort4*)&xnb[(size_t)pix*CC + c0] = yb;
}

// ---------------- LayerNorm f32 -> bf16 ----------------
__global__ void k_ln_bf16(const float* __restrict__ X, const float* __restrict__ g,
                          const float* __restrict__ be, bf16u* __restrict__ Y){
  int row = blockIdx.x;
  int t = threadIdx.x;
  float v = X[(size_t)row*CC + t];
  float s = v, s2 = v*v;
#pragma unroll
  for (int off = 32; off; off >>= 1){
    s  += __shfl_down(s,  off);
    s2 += __shfl_down(s2, off);
  }
  __shared__ float red[10];
  int wv_ = t >> 6, ln = t & 63;
  if (ln == 0){ red[wv_] = s; red[4+wv_] = s2; }
  __syncthreads();
  if (t == 0){
    float S  = red[0]+red[1]+red[2]+red[3];
    float S2 = red[4]+red[5]+red[6]+red[7];
    float mean = S * (1.f/CC);
    float var  = S2 * (1.f/CC) - mean*mean;
    red[8] = mean; red[9] = rsqrtf(var + EPS_LN);
  }
  __syncthreads();
  float mean = red[8], rstd = red[9];
  Y[(size_t)row*CC + t] = f2bf_r((v - mean) * rstd * g[t] + be[t]);
}

// ---------------- adaptive avg pool (reads bf16 xnb) ----------------
__global__ void k_pool(const bf16u* __restrict__ xnb, float* __restrict__ praw){
  int bp = blockIdx.x;
  int b = bp / PP, p = bp % PP;
  int ps, pi;
  if (p < 144)      { ps = 12; pi = p; }
  else if (p < 400) { ps = 16; pi = p - 144; }
  else if (p < 800) { ps = 20; pi = p - 400; }
  else              { ps = 24; pi = p - 800; }
  int oi = pi / ps, oj = pi % ps;
  int si = oi*HH/ps, ei = ((oi+1)*HH + ps - 1)/ps;
  int sj = oj*WW/ps, ej = ((oj+1)*WW + ps - 1)/ps;
  int c = threadIdx.x;
  const bf16u* xb = xnb + (size_t)b*NN*CC + c;
  float acc = 0.f;
  for (int i = si; i < ei; i++)
    for (int j = sj; j < ej; j++)
      acc += bf2f(xb[(size_t)(i*WW+j)*CC]);
  praw[(size_t)bp*CC + c] = acc / (float)((ei-si)*(ej-sj));
}

// ---------------- pool-dwconv + attn-norm fused -> bf16 ----------------
__global__ void k_pooldw_ln(const float* __restrict__ praw,
    const float* w0, const float* b0, const float* w1, const float* b1,
    const float* w2, const float* b2, const float* w3, const float* b3,
    const float* __restrict__ g, const float* __restrict__ be,
    bf16u* __restrict__ pools){
  int bp = blockIdx.x;
  int b = bp / PP, p = bp % PP;
  int ps, pi, off; const float *w, *bi;
  if (p < 144)      { ps=12; pi=p;     off=0;   w=w0; bi=b0; }
  else if (p < 400) { ps=16; pi=p-144; off=144; w=w1; bi=b1; }
  else if (p < 800) { ps=20; pi=p-400; off=400; w=w2; bi=b2; }
  else              { ps=24; pi=p-800; off=800; w=w3; bi=b3; }
  int oi = pi/ps, oj = pi%ps;
  int c = threadIdx.x;
  const float* base = praw + (size_t)(b*PP + off)*CC + c;
  float acc = bi[c];
#pragma unroll
  for (int kh = 0; kh < 3; kh++){
    int ii = oi + kh - 1; if (ii < 0 || ii >= ps) continue;
#pragma unroll
    for (int kw = 0; kw < 3; kw++){
      int jj = oj + kw - 1; if (jj < 0 || jj >= ps) continue;
      acc += base[(size_t)(ii*ps+jj)*CC] * w[c*9 + kh*3 + kw];
    }
  }
  float v = base[(size_t)(oi*ps+oj)*CC] + acc;
  float s = v, s2 = v*v;
#pragma unroll
  for (int o2_ = 32; o2_; o2_ >>= 1){
    s  += __shfl_down(s,  o2_);
    s2 += __shfl_down(s2, o2_);
  }
  __shared__ float red[10];
  int wv_ = c >> 6, ln = c & 63;
  if (ln == 0){ red[wv_] = s; red[4+wv_] = s2; }
  __syncthreads();
  if (c == 0){
    float S  = red[0]+red[1]+red[2]+red[3];
    float S2 = red[4]+red[5]+red[6]+red[7];
    float mean = S * (1.f/CC);
    float var  = S2 * (1.f/CC) - mean*mean;
    red[8] = mean; red[9] = rsqrtf(var + EPS_LN);
  }
  __syncthreads();
  float mean = red[8], rstd = red[9];
  pools[(size_t)bp*CC + c] = f2bf_r((v - mean) * rstd * g[c] + be[c]);
}

// ===== MFMA GEMM, bf16: Out = act(oscale*(A @ W^T) + bias) (+Res); NT = 128 or 64 =====
// VT_OUT: cols >= CC are the V-half of the kv projection -> written transposed to
// vtout[b][col-CC][p] (k_vt fused into the epilogue).
#define GST 40
template<int NT, bool OUT_BF16, bool HAS_BIAS, bool DO_GELU, bool HAS_RES, bool VT_OUT>
__global__ __launch_bounds__(256) void k_gemm_mfma(const bf16u* __restrict__ A,
                       const bf16u* __restrict__ Wt,
                       const float* __restrict__ bias, void* Outp,
                       const float* Res, bf16u* __restrict__ vtout,
                       int M, int Nout, int K, float oscale){
  constexpr int NW = (NT == 128) ? 4 : 2;
  __shared__ bf16u Ash[128*GST];
  __shared__ bf16u Bsh[NT*GST];
  int t = threadIdx.x;
  int wave = t >> 6, lane = t & 63, quad = lane >> 4, l16 = lane & 15;
  int m0 = blockIdx.y * 128, n0 = blockIdx.x * NT;
  int wm = (wave >> 1) * 64;
  int wn = (wave & 1) * (NT/2);
  int srow = t >> 1, scol = (t & 1) * 16;
  f32x4 zero = {0.f,0.f,0.f,0.f};
  f32x4 acc[4][NW];
#pragma unroll
  for (int i = 0; i < 4; i++)
#pragma unroll
    for (int j = 0; j < NW; j++) acc[i][j] = zero;
  for (int k0 = 0; k0 < K; k0 += 32){
    __syncthreads();
    {
      const bf16u* ap = A + (size_t)(m0+srow)*K + k0 + scol;
      uint4 u = *(const uint4*)ap;
      uint4 v = *(const uint4*)(ap+8);
      *(uint4*)&Ash[srow*GST + scol]     = u;
      *(uint4*)&Ash[srow*GST + scol + 8] = v;
    }
    if constexpr (NT == 128){
      const bf16u* bp = Wt + (size_t)(n0+srow)*K + k0 + scol;
      uint4 u = *(const uint4*)bp;
      uint4 v = *(const uint4*)(bp+8);
      *(uint4*)&Bsh[srow*GST + scol]     = u;
      *(uint4*)&Bsh[srow*GST + scol + 8] = v;
    } else {
      int br = t >> 2, bc = (t & 3) * 8;
      const bf16u* bp = Wt + (size_t)(n0+br)*K + k0 + bc;
      uint4 u = *(const uint4*)bp;
      *(uint4*)&Bsh[br*GST + bc] = u;
    }
    __syncthreads();
    short8 af[4], bfr[NW];
#pragma unroll
    for (int mi = 0; mi < 4; mi++)
      af[mi] = *(const short8*)&Ash[(wm + mi*16 + l16)*GST + quad*8];
#pragma unroll
    for (int ni = 0; ni < NW; ni++)
      bfr[ni] = *(const short8*)&Bsh[(wn + ni*16 + l16)*GST + quad*8];
#pragma unroll
    for (int mi = 0; mi < 4; mi++)
#pragma unroll
      for (int ni = 0; ni < NW; ni++)
        acc[mi][ni] = __builtin_amdgcn_mfma_f32_16x16x32_bf16(af[mi], bfr[ni], acc[mi][ni], 0,0,0);
  }
#pragma unroll
  for (int mi = 0; mi < 4; mi++){
#pragma unroll
    for (int r = 0; r < 4; r++){
      int row = m0 + wm + mi*16 + quad*4 + r;
#pragma unroll
      for (int ni = 0; ni < NW; ni++){
        int col = n0 + wn + ni*16 + l16;
        float v = acc[mi][ni][r] * oscale;
        if constexpr (HAS_BIAS) v += bias[col];
        if constexpr (DO_GELU)  v = 0.5f*v*(1.f + erff(v*0.70710678118654752f));
        if constexpr (HAS_RES)  v += Res[(size_t)row*Nout + col];
        if constexpr (VT_OUT){
          if (col < CC){
            ((bf16u*)Outp)[(size_t)row*Nout + col] = f2bf_r(v);
          } else {
            int bb = row / PP, pp = row - bb*PP;
            vtout[((size_t)(bb*CC + (col - CC)))*PPAD + pp] = f2bf_r(v);
          }
        } else if constexpr (OUT_BF16){
          ((bf16u*)Outp)[(size_t)row*Nout + col] = f2bf_r(v);
        } else {
          ((float*)Outp)[(size_t)row*Nout + col] = v;
        }
      }
    }
  }
}

// ============ MFMA flash attention: 64 q x 2 heads per block, 64-key chunks ============
// R9 structure (single-buffer, inline frag loads, ~64 VGPR). K from kvb [p][dims],
// V from pre-transposed vt [d][p] — both pure uint4 staging copies. S^T orientation
// (A=K, B=Q): b64 P writes, same-wave A-frag read-back (no barrier). PST=40 keeps
// LDS at 28.7 KB (5 blocks/CU). Tail chunk masks keys >= PP by skipping blocks 2,3
// and kc=1 (1344+32 == PP).
#define KST 72
#define VST 72
#define PST 40
__global__ __launch_bounds__(256) void k_attn_mfma(const bf16u* __restrict__ q,
                       const bf16u* __restrict__ kvb, const bf16u* __restrict__ vt,
                       bf16u* __restrict__ out){
  __shared__ bf16u Ksh[64*KST];          // [key][64 dims (2 heads)]
  __shared__ bf16u Vsh[64*VST];          // [d (2 heads x 32)][64 keys]
  __shared__ bf16u Psh[4][2][16*PST];    // [wave][head][q][64 keys]
  int t = threadIdx.x;
  int wave = t >> 6, lane = t & 63, quad = lane >> 4, l16 = lane & 15;
  int bid = blockIdx.x;
  int qt = bid % (NN/64);
  int hp = (bid / (NN/64)) % (NHEAD/2);
  int b  = bid / ((NN/64)*(NHEAD/2));
  int q0 = qt*64 + wave*16;
  const bf16u* qptr = q + (size_t)(b*NN + q0 + l16)*CC + hp*64 + quad*8;
  short8 qf0 = *(const short8*)qptr;
  short8 qf1 = *(const short8*)(qptr + HD);
  f32x4 zero = {0.f,0.f,0.f,0.f};
  f32x4 o00 = zero, o01 = zero, o10 = zero, o11 = zero;
  float ls0 = 0.f, ls1 = 0.f;
  int sr = t >> 2, sc = (t & 3) * 16;
  const bf16u* ksrc = kvb + (size_t)(b*PP + sr)*(2*CC) + hp*64 + sc;
  const bf16u* vsrc = vt  + (size_t)(b*CC + hp*64 + sr)*PPAD + sc;
  uint4 ka = *(const uint4*)ksrc, kb = *(const uint4*)(ksrc+8);
  uint4 va = *(const uint4*)vsrc, vb = *(const uint4*)(vsrc+8);

#define DO_BLK(blk) { \
    short8 kf0 = *(const short8*)&Ksh[(blk*16 + l16)*KST + quad*8]; \
    short8 kf1 = *(const short8*)&Ksh[(blk*16 + l16)*KST + 32 + quad*8]; \
    f32x4 s0 = __builtin_amdgcn_mfma_f32_16x16x32_bf16(kf0, qf0, zero, 0,0,0); \
    f32x4 s1 = __builtin_amdgcn_mfma_f32_16x16x32_bf16(kf1, qf1, zero, 0,0,0); \
    float e0a = __builtin_amdgcn_exp2f(s0[0]), e0b = __builtin_amdgcn_exp2f(s0[1]); \
    float e0c = __builtin_amdgcn_exp2f(s0[2]), e0d = __builtin_amdgcn_exp2f(s0[3]); \
    float e1a = __builtin_amdgcn_exp2f(s1[0]), e1b = __builtin_amdgcn_exp2f(s1[1]); \
    float e1c = __builtin_amdgcn_exp2f(s1[2]), e1d = __builtin_amdgcn_exp2f(s1[3]); \
    ls0 += (e0a+e0b)+(e0c+e0d); ls1 += (e1a+e1b)+(e1c+e1d); \
    ushort4 pa = {f2bf_r(e0a), f2bf_r(e0b), f2bf_r(e0c), f2bf_r(e0d)}; \
    ushort4 pb = {f2bf_r(e1a), f2bf_r(e1b), f2bf_r(e1c), f2bf_r(e1d)}; \
    *(ushort4*)&P0[l16*PST + blk*16 + quad*4] = pa; \
    *(ushort4*)&P1[l16*PST + blk*16 + quad*4] = pb; }

#define DO_PV(kc) { \
    short8 pf0 = *(const short8*)&P0[l16*PST + kc*32 + quad*8]; \
    short8 pf1 = *(const short8*)&P1[l16*PST + kc*32 + quad*8]; \
    short8 vf00 = *(const short8*)&Vsh[(     l16)*VST + kc*32 + quad*8]; \
    short8 vf01 = *(const short8*)&Vsh[(16 + l16)*VST + kc*32 + quad*8]; \
    short8 vf10 = *(const short8*)&Vsh[(32 + l16)*VST + kc*32 + quad*8]; \
    short8 vf11 = *(const short8*)&Vsh[(48 + l16)*VST + kc*32 + quad*8]; \
    o00 = __builtin_amdgcn_mfma_f32_16x16x32_bf16(pf0, vf00, o00, 0,0,0); \
    o01 = __builtin_amdgcn_mfma_f32_16x16x32_bf16(pf0, vf01, o01, 0,0,0); \
    o10 = __builtin_amdgcn_mfma_f32_16x16x32_bf16(pf1, vf10, o10, 0,0,0); \
    o11 = __builtin_amdgcn_mfma_f32_16x16x32_bf16(pf1, vf11, o11, 0,0,0); }

  for (int ch = 0; ch < PPAD/64; ch++){
    __syncthreads();
    *(uint4*)&Ksh[sr*KST + sc]     = ka;
    *(uint4*)&Ksh[sr*KST + sc + 8] = kb;
    *(uint4*)&Vsh[sr*VST + sc]     = va;
    *(uint4*)&Vsh[sr*VST + sc + 8] = vb;
    if (ch < PPAD/64 - 1){
      ksrc += (size_t)64*(2*CC); vsrc += 64;
      ka = *(const uint4*)ksrc; kb = *(const uint4*)(ksrc+8);
      va = *(const uint4*)vsrc; vb = *(const uint4*)(vsrc+8);
    }
    __syncthreads();
    bf16u* P0 = &Psh[wave][0][0];
    bf16u* P1 = &Psh[wave][1][0];
    if (ch < PPAD/64 - 1){
      DO_BLK(0) DO_BLK(1) DO_BLK(2) DO_BLK(3)
      DO_PV(0) DO_PV(1)
    } else {
      // tail: keys 1344..1375 valid, 1376..1407 masked off entirely
      DO_BLK(0) DO_BLK(1)
      DO_PV(0)
    }
  }
#undef DO_BLK
#undef DO_PV
  ls0 += __shfl_xor(ls0, 16); ls0 += __shfl_xor(ls0, 32);
  ls1 += __shfl_xor(ls1, 16); ls1 += __shfl_xor(ls1, 32);
#pragma unroll
  for (int r = 0; r < 4; r++){
    int qq = quad*4 + r;
    float i0 = 1.f / __shfl(ls0, qq);
    float i1 = 1.f / __shfl(ls1, qq);
    size_t base = (size_t)(b*NN + q0 + qq)*CC + hp*64;
    out[base + l16     ] = f2bf_r(o00[r]*i0);
    out[base + 16 + l16] = f2bf_r(o01[r]*i0);
    out[base + 32 + l16] = f2bf_r(o10[r]*i1);
    out[base + 48 + l16] = f2bf_r(o11[r]*i1);
  }
}

// ---------------- h2 = h + dwconv3x3(h) + bias (hid=1024, bf16) ----------------
__global__ void k_dwh(const bf16u* __restrict__ h, const float* __restrict__ w,
                      const float* __restrict__ bias, bf16u* __restrict__ h2){
  int pix = blockIdx.x;
  int b = pix / NN, n = pix % NN;
  int hy = n / WW, wx = n % WW;
  int c0 = threadIdx.x * 4;
  float wv[4][9];
  float acc[4];
#pragma unroll
  for (int cc = 0; cc < 4; cc++){
    acc[cc] = bias[c0+cc];
#pragma unroll
    for (int k = 0; k < 9; k++) wv[cc][k] = w[(c0+cc)*9 + k];
  }
  const bf16u* hb = h + (size_t)b*NN*HIDN + c0;
#pragma unroll
  for (int kh = 0; kh < 3; kh++){
    int iy = hy + kh - 1; if (iy < 0 || iy >= HH) continue;
#pragma unroll
    for (int kw = 0; kw < 3; kw++){
      int ix = wx + kw - 1; if (ix < 0 || ix >= WW) continue;
      ushort4 hv = *(const ushort4*)&hb[(size_t)(iy*WW+ix)*HIDN];
      int k = kh*3+kw;
      acc[0] += bf2f(hv.x)*wv[0][k]; acc[1] += bf2f(hv.y)*wv[1][k];
      acc[2] += bf2f(hv.z)*wv[2][k]; acc[3] += bf2f(hv.w)*wv[3][k];
    }
  }
  ushort4 cv = *(const ushort4*)&hb[(size_t)n*HIDN];
  ushort4 o;
  o.x = f2bf_r(bf2f(cv.x) + acc[0]); o.y = f2bf_r(bf2f(cv.y) + acc[1]);
  o.z = f2bf_r(bf2f(cv.z) + acc[2]); o.w = f2bf_r(bf2f(cv.w) + acc[3]);
  *(ushort4*)&h2[(size_t)pix*HIDN + c0] = o;
}

extern "C" void kernel_launch(void* const* d_in, const int* in_sizes, int n_in,
                              void* d_out, int out_size, void* d_ws, size_t ws_size,
                              hipStream_t stream){
  const float* x      = (const float*)d_in[0];
  const float* cpe_w  = (const float*)d_in[1];
  const float* cpe_b  = (const float*)d_in[2];
  const float* n1w    = (const float*)d_in[3];
  const float* n1b    = (const float*)d_in[4];
  const float* q_w    = (const float*)d_in[5];
  const float* kv_w   = (const float*)d_in[6];
  const float* anw    = (const float*)d_in[7];
  const float* anb    = (const float*)d_in[8];
  const float* proj_w = (const float*)d_in[9];
  const float* proj_b = (const float*)d_in[10];
  const float* n2w    = (const float*)d_in[11];
  const float* n2b    = (const float*)d_in[12];
  const float* fc1_w  = (const float*)d_in[13];
  const float* fc1_b  = (const float*)d_in[14];
  const float* irb_w  = (const float*)d_in[15];
  const float* irb_b  = (const float*)d_in[16];
  const float* fc2_w  = (const float*)d_in[17];
  const float* fc2_b  = (const float*)d_in[18];
  const float* dw0    = (const float*)d_in[21];
  const float* db0    = (const float*)d_in[22];
  const float* dw1    = (const float*)d_in[23];
  const float* db1    = (const float*)d_in[24];
  const float* dw2    = (const float*)d_in[25];
  const float* db2    = (const float*)d_in[26];
  const float* dw3    = (const float*)d_in[27];
  const float* db3    = (const float*)d_in[28];

  const size_t BNC = (size_t)BQ*NN*CC;
  const size_t BPC = (size_t)BQ*PP*CC;
  const size_t BNH = (size_t)BQ*NN*HIDN;

  float* x1   = (float*)d_ws;
  bf16u* xnb  = (bf16u*)(x1 + BNC);
  bf16u* wbuf = xnb + BNC;
  bf16u* wq   = wbuf;
  bf16u* wkv  = wbuf + 65536;
  bf16u* wpj  = wbuf + 196608;
  bf16u* wf1  = wbuf + 262144;
  bf16u* wf2  = wbuf + 524288;
  float* A0   = (float*)(wbuf + 786432);
  bf16u* qb   = (bf16u*)A0;
  float* praw = (float*)(qb + BNC);
  bf16u* poolsb = (bf16u*)(praw + BPC);
  bf16u* kvb  = poolsb + BPC;                 // [BQ*PP][512] (V-half unused by attn)
  bf16u* vtb  = kvb + (size_t)BQ*PP*2*CC;     // [BQ*256][PPAD]
  bf16u* hbuf = (bf16u*)A0;                   // phase-2 overlay (qb dead after proj)
  bf16u* h2buf = hbuf + BNH;

  // 1. weights->bf16 (768 blocks) + CPE+residual+norm1 (3136 blocks), one launch
  k_init<<<768 + BQ*NN/4, 256, 0, stream>>>(q_w, kv_w, proj_w, fc1_w, fc2_w, wbuf,
                                            x, cpe_w, cpe_b, n1w, n1b, x1, xnb);
  // 2. q projection -> bf16 (pre-scaled), NT=64
  k_gemm_mfma<64,true,false,false,false,false><<<dim3(CC/64, BQ*NN/128), 256, 0, stream>>>(
      xnb, wq, nullptr, qb, nullptr, nullptr, BQ*NN, CC, CC, QSCALE_LOG2E);
  // 3. pyramid pooling (reads bf16 xnb)
  k_pool<<<BQ*PP, 256, 0, stream>>>(xnb, praw);
  // 4. pool dwconv + attn-norm -> bf16
  k_pooldw_ln<<<BQ*PP, 256, 0, stream>>>(praw, dw0,db0, dw1,db1, dw2,db2, dw3,db3,
                                         anw, anb, poolsb);
  // 5. kv projection -> bf16, NT=64; V-half written transposed to vtb in epilogue
  k_gemm_mfma<64,true,false,false,false,true><<<dim3(2*CC/64, BQ*PP/128), 256, 0, stream>>>(
      poolsb, wkv, nullptr, kvb, nullptr, vtb, BQ*PP, 2*CC, CC, 1.0f);
  // 6. MFMA attention (in-place: qb becomes attn output)
  k_attn_mfma<<<BQ*(NHEAD/2)*(NN/64), 256, 0, stream>>>(qb, kvb, vtb, qb);
  // 7. proj + bias + residual -> x1, NT=64
  k_gemm_mfma<64,false,true,false,true,false><<<dim3(CC/64, BQ*NN/128), 256, 0, stream>>>(
      qb, wpj, proj_b, x1, x1, nullptr, BQ*NN, CC, CC, 1.0f);
  // 8. norm2 -> bf16
  k_ln_bf16<<<BQ*NN, 256, 0, stream>>>(x1, n2w, n2b, xnb);
  // 9. fc1 + bias + gelu -> hbuf (bf16), NT=128
  k_gemm_mfma<128,true,true,true,false,false><<<dim3(HIDN/128, BQ*NN/128), 256, 0, stream>>>(
      xnb, wf1, fc1_b, hbuf, nullptr, nullptr, BQ*NN, HIDN, CC, 1.0f);
  // 10. h2 = h + dwconv(h)
  k_dwh<<<BQ*NN, 256, 0, stream>>>(hbuf, irb_w, irb_b, h2buf);
  // 11. fc2 + bias + residual -> d_out (f32), NT=64
  k_gemm_mfma<64,false,true,false,true,false><<<dim3(CC/64, BQ*NN/128), 256, 0, stream>>>(
      h2buf, wf2, fc2_b, d_out, x1, nullptr, BQ*NN, CC, HIDN, 1.0f);
}